// Round 4
// baseline (304.733 us; speedup 1.0000x reference)
//
#include <hip/hip_runtime.h>
#include <math.h>

#define NBINS 64
#define HIST_ELEMS (NBINS*NBINS)
// weight = exp2(-K2*(u_bins - b)^2), K2 = 8192/63^2*log2(e); fold sqrt(K2) into coords
#define SQK 1.7256062f

typedef float f4 __attribute__((ext_vector_type(4)));
typedef float f32x4 __attribute__((ext_vector_type(4)));
typedef _Float16 half8 __attribute__((ext_vector_type(8)));
typedef int int4v __attribute__((ext_vector_type(4)));

// ---- monotone float<->uint keys ----
static __device__ __forceinline__ unsigned f2key(float f) {
    unsigned u = __float_as_uint(f);
    return (u & 0x80000000u) ? ~u : (u | 0x80000000u);
}
static __device__ __forceinline__ float key2f(unsigned u) {
    return (u & 0x80000000u) ? __uint_as_float(u & 0x7fffffffu) : __uint_as_float(~u);
}

static __device__ __forceinline__ half8 pack8(const float* w) {
    int4v v;
    v[0] = __builtin_bit_cast(int, __builtin_amdgcn_cvt_pkrtz(w[0], w[1]));
    v[1] = __builtin_bit_cast(int, __builtin_amdgcn_cvt_pkrtz(w[2], w[3]));
    v[2] = __builtin_bit_cast(int, __builtin_amdgcn_cvt_pkrtz(w[4], w[5]));
    v[3] = __builtin_bit_cast(int, __builtin_amdgcn_cvt_pkrtz(w[6], w[7]));
    return __builtin_bit_cast(half8, v);
}

// ws layout: [0..7] uint minmax keys | @256: float hist[2][4096] | then float bh[2*GX][4096]
__global__ void init_ws_kernel(unsigned* __restrict__ mm, float* __restrict__ hist) {
    int i = threadIdx.x;
    if (i < 8) mm[i] = (i & 1) ? 0u : 0xFFFFFFFFu;
    f4* h4 = (f4*)hist;
    f4 z = {0.f, 0.f, 0.f, 0.f};
    for (int j = i; j < 2 * HIST_ELEMS / 4; j += blockDim.x) h4[j] = z;
}

__global__ __launch_bounds__(256) void minmax_kernel(const float* __restrict__ tar,
                                                     const float* __restrict__ src,
                                                     unsigned* __restrict__ mm, int P) {
    const int n = blockIdx.y;
    const int t = blockIdx.z;
    const f4* x = (const f4*)((t == 0 ? tar : src) + (size_t)n * P);
    const int n4 = P / 4;
    float lmin = INFINITY, lmax = -INFINITY;
    for (int i = blockIdx.x * blockDim.x + threadIdx.x; i < n4; i += gridDim.x * blockDim.x) {
        f4 v = x[i];
        lmin = fminf(lmin, fminf(fminf(v[0], v[1]), fminf(v[2], v[3])));
        lmax = fmaxf(lmax, fmaxf(fmaxf(v[0], v[1]), fmaxf(v[2], v[3])));
    }
    for (int off = 32; off > 0; off >>= 1) {
        lmin = fminf(lmin, __shfl_down(lmin, off, 64));
        lmax = fmaxf(lmax, __shfl_down(lmax, off, 64));
    }
    __shared__ float smin[4], smax[4];
    const int lane = threadIdx.x & 63, wave = threadIdx.x >> 6;
    if (lane == 0) { smin[wave] = lmin; smax[wave] = lmax; }
    __syncthreads();
    if (threadIdx.x == 0) {
        float m = fminf(fminf(smin[0], smin[1]), fminf(smin[2], smin[3]));
        float M = fmaxf(fmaxf(smax[0], smax[1]), fmaxf(smax[2], smax[3]));
        atomicMin(&mm[(n * 2 + t) * 2 + 0], f2key(m));
        atomicMax(&mm[(n * 2 + t) * 2 + 1], f2key(M));
    }
}

// Joint histogram as 64x64xP GEMM via MFMA f16, direct-from-global fragments.
// A[m][k]: m=lane&15 (+16*mt), k=quad*8+j ; B[k][n]: n=lane&15, k=quad*8+j
// C/D: col=lane&15, row=quad*4+reg.
// Each wave owns CHUNKS*32 consecutive points; lane loads its own 8 consecutive
// floats per chunk (quad-shared cachelines) -> no LDS staging, no K-loop barriers.
template <int CHUNKS, int STAGED>
__global__ __launch_bounds__(512, 4) void mfma_hist_kernel(const float* __restrict__ tar,
                                                           const float* __restrict__ src,
                                                           const unsigned* __restrict__ mm,
                                                           float* __restrict__ bh,
                                                           float* __restrict__ hist,
                                                           int P, int gx) {
    const int n = blockIdx.y;
    const int bx = blockIdx.x;
    const int tid = threadIdx.x;
    const int lane = tid & 63, wave = tid >> 6;
    const int mlane = lane & 15, quad = lane >> 4;

    __shared__ float lh[HIST_ELEMS];
    {
        f4 z = {0.f, 0.f, 0.f, 0.f};
        f4* l4 = (f4*)lh;
        for (int i = tid; i < HIST_ELEMS / 4; i += 512) l4[i] = z;
        // no barrier needed until after the main loop (lh untouched there)
    }

    const float tmin = key2f(mm[n * 4 + 0]);
    const float tmax = key2f(mm[n * 4 + 1]);
    const float smin = key2f(mm[n * 4 + 2]);
    const float smax = key2f(mm[n * 4 + 3]);
    const float tk = 63.0f / (tmax - tmin + 1e-10f) * SQK;
    const float sk = 63.0f / (smax - smin + 1e-10f) * SQK;

    // per-lane scaled bin centers: d = x*tk - ctr[mt]
    float ctr[4], csr[4];
    #pragma unroll
    for (int mt = 0; mt < 4; ++mt) {
        float b = SQK * (float)(mlane + 16 * mt);
        ctr[mt] = tmin * tk + b;
        csr[mt] = smin * sk + b;
    }

    const size_t base = (size_t)n * P + (size_t)bx * (256 * CHUNKS) + (size_t)wave * (32 * CHUNKS)
                        + (size_t)quad * 8;
    const float* t = tar + base;
    const float* s = src + base;

    f32x4 acc[4][4];
    #pragma unroll
    for (int a = 0; a < 4; ++a)
        #pragma unroll
        for (int b = 0; b < 4; ++b) acc[a][b] = (f32x4){0.f, 0.f, 0.f, 0.f};

    #pragma unroll 2
    for (int c = 0; c < CHUNKS; ++c) {
        f4 t0 = *(const f4*)(t + c * 32);
        f4 t1 = *(const f4*)(t + c * 32 + 4);
        f4 s0 = *(const f4*)(s + c * 32);
        f4 s1 = *(const f4*)(s + c * 32 + 4);
        float xt[8] = {t0[0], t0[1], t0[2], t0[3], t1[0], t1[1], t1[2], t1[3]};
        float xs[8] = {s0[0], s0[1], s0[2], s0[3], s1[0], s1[1], s1[2], s1[3]};

        half8 af[4], bf[4];
        #pragma unroll
        for (int mt = 0; mt < 4; ++mt) {
            float w[8];
            #pragma unroll
            for (int j = 0; j < 8; ++j) {
                float d = fmaf(xt[j], tk, -ctr[mt]);
                w[j] = __builtin_amdgcn_exp2f(-(d * d));
            }
            af[mt] = pack8(w);
        }
        #pragma unroll
        for (int nt = 0; nt < 4; ++nt) {
            float w[8];
            #pragma unroll
            for (int j = 0; j < 8; ++j) {
                float d = fmaf(xs[j], sk, -csr[nt]);
                w[j] = __builtin_amdgcn_exp2f(-(d * d));
            }
            bf[nt] = pack8(w);
        }
        #pragma unroll
        for (int mt = 0; mt < 4; ++mt)
            #pragma unroll
            for (int nt = 0; nt < 4; ++nt)
                acc[mt][nt] = __builtin_amdgcn_mfma_f32_16x16x32_f16(
                    af[mt], bf[nt], acc[mt][nt], 0, 0, 0);
    }
    __syncthreads();   // lh zeroing (pre-loop) complete block-wide

    // combine 8 waves' 64x64 accumulators in LDS
    #pragma unroll
    for (int mt = 0; mt < 4; ++mt)
        #pragma unroll
        for (int nt = 0; nt < 4; ++nt)
            #pragma unroll
            for (int r = 0; r < 4; ++r) {
                int row = 16 * mt + 4 * quad + r;
                int col = 16 * nt + mlane;
                unsafeAtomicAdd(&lh[row * NBINS + col], acc[mt][nt][r]);
            }
    __syncthreads();

    if (STAGED) {
        f4* dst = (f4*)(bh + ((size_t)n * gx + bx) * HIST_ELEMS);
        const f4* l4 = (const f4*)lh;
        for (int i = tid; i < HIST_ELEMS / 4; i += 512) dst[i] = l4[i];
    } else {
        float* gh = hist + (size_t)n * HIST_ELEMS;
        for (int i = tid; i < HIST_ELEMS; i += 512) unsafeAtomicAdd(&gh[i], lh[i]);
    }
}

__global__ __launch_bounds__(256) void reduce_kernel(const float* __restrict__ bh,
                                                     float* __restrict__ hist, int gx) {
    const int g = blockIdx.x * 256 + threadIdx.x;   // 0..8191
    const int n = g >> 12, e = g & 4095;
    const float* p = bh + ((size_t)n * gx) * HIST_ELEMS + e;
    float sum = 0.0f;
    #pragma unroll 8
    for (int b = 0; b < gx; ++b) sum += p[(size_t)b * HIST_ELEMS];
    hist[g] = sum;
}

static __device__ __forceinline__ float block_reduce_sum(float v, float* buf) {
    for (int off = 32; off > 0; off >>= 1) v += __shfl_down(v, off, 64);
    const int lane = threadIdx.x & 63, wave = threadIdx.x >> 6;
    __syncthreads();
    if (lane == 0) buf[wave] = v;
    __syncthreads();
    return buf[0] + buf[1] + buf[2] + buf[3];
}

__global__ __launch_bounds__(256) void finalize_kernel(const float* __restrict__ ghist,
                                                       float* __restrict__ out) {
    __shared__ float buf[4];
    __shared__ float colp[4][NBINS];
    __shared__ float rowsum[NBINS], colsum[NBINS];
    const int tid = threadIdx.x;
    float acc = 0.0f;
    for (int n = 0; n < 2; ++n) {
        const float* h = ghist + n * HIST_ELEMS;
        {
            int r = tid >> 2, q = tid & 3;
            const float* hp = h + r * NBINS + q * 16;
            float sv = 0.0f;
            #pragma unroll
            for (int k = 0; k < 16; ++k) sv += hp[k];
            sv += __shfl_down(sv, 1, 64);
            sv += __shfl_down(sv, 2, 64);
            if (q == 0) rowsum[r] = sv;
        }
        {
            int c = tid & 63, g = tid >> 6;
            const float* hp = h + (g * 16) * NBINS + c;
            float sv = 0.0f;
            #pragma unroll
            for (int k = 0; k < 16; ++k) sv += hp[k * NBINS];
            colp[g][c] = sv;
        }
        __syncthreads();
        if (tid < NBINS)
            colsum[tid] = colp[0][tid] + colp[1][tid] + colp[2][tid] + colp[3][tid];
        __syncthreads();

        float tv = (tid < NBINS) ? rowsum[tid] : 0.0f;
        float total = block_reduce_sum(tv, buf);
        float inv = 1.0f / total;

        float ej = 0.0f;
        for (int i = tid; i < HIST_ELEMS; i += 256) {
            float p = h[i] * inv;
            ej += p * __logf(p + 1e-10f);
        }
        float entj = -block_reduce_sum(ej, buf);

        float em = 0.0f;
        if (tid < NBINS) {
            float p = rowsum[tid] * inv;
            em = p * __logf(p + 1e-10f);
        } else if (tid < 2 * NBINS) {
            float p = colsum[tid - NBINS] * inv;
            em = p * __logf(p + 1e-10f);
        }
        float ents = -block_reduce_sum(em, buf);

        acc += ents / entj;
        __syncthreads();
    }
    if (tid == 0) out[0] = -0.5f * acc;
}

extern "C" void kernel_launch(void* const* d_in, const int* in_sizes, int n_in,
                              void* d_out, int out_size, void* d_ws, size_t ws_size,
                              hipStream_t stream) {
    const float* tar = (const float*)d_in[0];
    const float* src = (const float*)d_in[1];
    const int N = 2;
    const int P = in_sizes[0] / N;  // 884736

    unsigned* mm = (unsigned*)d_ws;
    float* hist = (float*)((char*)d_ws + 256);
    float* bh = (float*)((char*)d_ws + 256 + 2 * HIST_ELEMS * sizeof(float));
    float* out = (float*)d_out;

    const size_t fixed = 256 + (size_t)2 * HIST_ELEMS * 4;
    const size_t need432 = fixed + (size_t)2 * 432 * HIST_ELEMS * 4;  // ~13.9 MB
    const size_t need216 = fixed + (size_t)2 * 216 * HIST_ELEMS * 4;  // ~7.1 MB

    init_ws_kernel<<<1, 256, 0, stream>>>(mm, hist);
    minmax_kernel<<<dim3(64, N, 2), 256, 0, stream>>>(tar, src, mm, P);

    if (ws_size >= need432) {
        // 2048 pts/block, 8 waves of 256 pts (8 chunks)
        mfma_hist_kernel<8, 1><<<dim3(432, N), 512, 0, stream>>>(tar, src, mm, bh, hist, P, 432);
        reduce_kernel<<<32, 256, 0, stream>>>(bh, hist, 432);
    } else if (ws_size >= need216) {
        mfma_hist_kernel<16, 1><<<dim3(216, N), 512, 0, stream>>>(tar, src, mm, bh, hist, P, 216);
        reduce_kernel<<<32, 256, 0, stream>>>(bh, hist, 216);
    } else {
        mfma_hist_kernel<16, 0><<<dim3(216, N), 512, 0, stream>>>(tar, src, mm, bh, hist, P, 216);
    }
    finalize_kernel<<<1, 256, 0, stream>>>(hist, out);
}

// Round 5
// 288.029 us; speedup vs baseline: 1.0580x; 1.0580x over previous
//
#include <hip/hip_runtime.h>
#include <math.h>

#define NBINS 64
#define HIST_ELEMS (NBINS*NBINS)
#define PTS_PER_BLOCK 2048
#define GX 432                  // 432 * 2048 = 884736 = P
// weight = exp2(-K2*(u_bins - b)^2), K2 = 8192/63^2*log2(e); fold sqrt(K2) into coords
#define SQK 1.7256062f

typedef float f4 __attribute__((ext_vector_type(4)));
typedef float f32x4 __attribute__((ext_vector_type(4)));
typedef _Float16 half8 __attribute__((ext_vector_type(8)));
typedef int int4v __attribute__((ext_vector_type(4)));

// ---- monotone float<->uint keys ----
static __device__ __forceinline__ unsigned f2key(float f) {
    unsigned u = __float_as_uint(f);
    return (u & 0x80000000u) ? ~u : (u | 0x80000000u);
}
static __device__ __forceinline__ float key2f(unsigned u) {
    return (u & 0x80000000u) ? __uint_as_float(u & 0x7fffffffu) : __uint_as_float(~u);
}

static __device__ __forceinline__ half8 pack8(const float* w) {
    int4v v;
    v[0] = __builtin_bit_cast(int, __builtin_amdgcn_cvt_pkrtz(w[0], w[1]));
    v[1] = __builtin_bit_cast(int, __builtin_amdgcn_cvt_pkrtz(w[2], w[3]));
    v[2] = __builtin_bit_cast(int, __builtin_amdgcn_cvt_pkrtz(w[4], w[5]));
    v[3] = __builtin_bit_cast(int, __builtin_amdgcn_cvt_pkrtz(w[6], w[7]));
    return __builtin_bit_cast(half8, v);
}

// ws layout: [0..7] uint minmax keys | @256: float hist[2][4096] | then float bh[2*GX][4096]
__global__ void init_ws_kernel(unsigned* __restrict__ mm, float* __restrict__ hist) {
    int i = threadIdx.x;
    if (i < 8) mm[i] = (i & 1) ? 0u : 0xFFFFFFFFu;
    f4* h4 = (f4*)hist;
    f4 z = {0.f, 0.f, 0.f, 0.f};
    for (int j = i; j < 2 * HIST_ELEMS / 4; j += blockDim.x) h4[j] = z;
}

__global__ __launch_bounds__(256) void minmax_kernel(const float* __restrict__ tar,
                                                     const float* __restrict__ src,
                                                     unsigned* __restrict__ mm, int P) {
    const int n = blockIdx.y;
    const int t = blockIdx.z;
    const f4* x = (const f4*)((t == 0 ? tar : src) + (size_t)n * P);
    const int n4 = P / 4;
    float lmin = INFINITY, lmax = -INFINITY;
    for (int i = blockIdx.x * blockDim.x + threadIdx.x; i < n4; i += gridDim.x * blockDim.x) {
        f4 v = x[i];
        lmin = fminf(lmin, fminf(fminf(v[0], v[1]), fminf(v[2], v[3])));
        lmax = fmaxf(lmax, fmaxf(fmaxf(v[0], v[1]), fmaxf(v[2], v[3])));
    }
    for (int off = 32; off > 0; off >>= 1) {
        lmin = fminf(lmin, __shfl_down(lmin, off, 64));
        lmax = fmaxf(lmax, __shfl_down(lmax, off, 64));
    }
    __shared__ float smin[4], smax[4];
    const int lane = threadIdx.x & 63, wave = threadIdx.x >> 6;
    if (lane == 0) { smin[wave] = lmin; smax[wave] = lmax; }
    __syncthreads();
    if (threadIdx.x == 0) {
        float m = fminf(fminf(smin[0], smin[1]), fminf(smin[2], smin[3]));
        float M = fmaxf(fmaxf(smax[0], smax[1]), fmaxf(smax[2], smax[3]));
        atomicMin(&mm[(n * 2 + t) * 2 + 0], f2key(m));
        atomicMax(&mm[(n * 2 + t) * 2 + 1], f2key(M));
    }
}

// Joint histogram as 64x64xP GEMM via MFMA f16, LDS-staged.
// A[m][k]: m=lane&15 (+16*mt), k=quad*8+j ; B[k][n]: n=lane&15, k=quad*8+j
// C/D: col=lane&15, row=quad*4+reg.
// One coalesced staging phase + ONE barrier per block; waves then run 8
// LDS-fed K=32 chunks with no further barriers until the epilogue.
template <int STAGED>
__global__ __launch_bounds__(512, 4) void mfma_hist_kernel(const float* __restrict__ tar,
                                                           const float* __restrict__ src,
                                                           const unsigned* __restrict__ mm,
                                                           float* __restrict__ bh,
                                                           float* __restrict__ hist,
                                                           int P) {
    const int n = blockIdx.y;
    const int bx = blockIdx.x;
    const int tid = threadIdx.x;
    const int lane = tid & 63, wave = tid >> 6;
    const int mlane = lane & 15, quad = lane >> 4;

    __shared__ float su_t[PTS_PER_BLOCK], su_s[PTS_PER_BLOCK];
    __shared__ float lh[HIST_ELEMS];
    {
        f4 z = {0.f, 0.f, 0.f, 0.f};
        f4* l4 = (f4*)lh;
        #pragma unroll
        for (int i = 0; i < 2; ++i) l4[tid + i * 512] = z;
    }

    const float tmin = key2f(mm[n * 4 + 0]);
    const float tmax = key2f(mm[n * 4 + 1]);
    const float smin = key2f(mm[n * 4 + 2]);
    const float smax = key2f(mm[n * 4 + 3]);
    const float tk = 63.0f / (tmax - tmin + 1e-10f) * SQK;
    const float sk = 63.0f / (smax - smin + 1e-10f) * SQK;
    const float toff = tmin * tk, soff = smin * sk;

    // stage: coalesced global float4 -> scaled coords -> LDS
    {
        const size_t gbase = (size_t)n * P + (size_t)bx * PTS_PER_BLOCK + tid * 4;
        f4 tv = *(const f4*)(tar + gbase);
        f4 sv = *(const f4*)(src + gbase);
        f4 utv, usv;
        #pragma unroll
        for (int c = 0; c < 4; ++c) {
            utv[c] = fmaf(tv[c], tk, -toff);
            usv[c] = fmaf(sv[c], sk, -soff);
        }
        *(f4*)&su_t[tid * 4] = utv;
        *(f4*)&su_s[tid * 4] = usv;
    }
    __syncthreads();   // staging + lh zeroing complete

    float binc[4];
    #pragma unroll
    for (int mt = 0; mt < 4; ++mt) binc[mt] = SQK * (float)(mlane + 16 * mt);

    f32x4 acc[4][4];
    #pragma unroll
    for (int a = 0; a < 4; ++a)
        #pragma unroll
        for (int b = 0; b < 4; ++b) acc[a][b] = (f32x4){0.f, 0.f, 0.f, 0.f};

    const int kwbase = wave * 256 + quad * 8;
    #pragma unroll 2
    for (int c = 0; c < 8; ++c) {
        const int kbase = kwbase + c * 32;
        f4 ta = *(const f4*)&su_t[kbase];
        f4 tb = *(const f4*)&su_t[kbase + 4];
        f4 sa = *(const f4*)&su_s[kbase];
        f4 sb = *(const f4*)&su_s[kbase + 4];
        float xt[8] = {ta[0], ta[1], ta[2], ta[3], tb[0], tb[1], tb[2], tb[3]};
        float xs[8] = {sa[0], sa[1], sa[2], sa[3], sb[0], sb[1], sb[2], sb[3]};

        half8 af[4], bf[4];
        #pragma unroll
        for (int mt = 0; mt < 4; ++mt) {
            float w[8];
            #pragma unroll
            for (int j = 0; j < 8; ++j) {
                float d = xt[j] - binc[mt];
                w[j] = __builtin_amdgcn_exp2f(-(d * d));
            }
            af[mt] = pack8(w);
        }
        #pragma unroll
        for (int nt = 0; nt < 4; ++nt) {
            float w[8];
            #pragma unroll
            for (int j = 0; j < 8; ++j) {
                float d = xs[j] - binc[nt];
                w[j] = __builtin_amdgcn_exp2f(-(d * d));
            }
            bf[nt] = pack8(w);
        }
        #pragma unroll
        for (int mt = 0; mt < 4; ++mt)
            #pragma unroll
            for (int nt = 0; nt < 4; ++nt)
                acc[mt][nt] = __builtin_amdgcn_mfma_f32_16x16x32_f16(
                    af[mt], bf[nt], acc[mt][nt], 0, 0, 0);
    }

    // combine 8 waves' 64x64 accumulators in LDS (lh zeroed before barrier above)
    #pragma unroll
    for (int mt = 0; mt < 4; ++mt)
        #pragma unroll
        for (int nt = 0; nt < 4; ++nt)
            #pragma unroll
            for (int r = 0; r < 4; ++r) {
                int row = 16 * mt + 4 * quad + r;
                int col = 16 * nt + mlane;
                unsafeAtomicAdd(&lh[row * NBINS + col], acc[mt][nt][r]);
            }
    __syncthreads();

    if (STAGED) {
        f4* dst = (f4*)(bh + ((size_t)n * GX + bx) * HIST_ELEMS);
        const f4* l4 = (const f4*)lh;
        #pragma unroll
        for (int i = 0; i < 2; ++i) dst[tid + i * 512] = l4[tid + i * 512];
    } else {
        float* gh = hist + (size_t)n * HIST_ELEMS;
        for (int i = tid; i < HIST_ELEMS; i += 512) unsafeAtomicAdd(&gh[i], lh[i]);
    }
}

#define RSEGS 4
__global__ __launch_bounds__(256) void reduce_kernel(const float* __restrict__ bh,
                                                     float* __restrict__ hist) {
    const int eb = blockIdx.x & 31;        // elem block 0..31
    const int seg = blockIdx.x >> 5;       // tile segment 0..3
    const int g = eb * 256 + threadIdx.x;  // 0..8191
    const int n = g >> 12, e = g & 4095;
    const int b0 = seg * (GX / RSEGS);
    const float* p = bh + ((size_t)n * GX + b0) * HIST_ELEMS + e;
    float sum = 0.0f;
    #pragma unroll 8
    for (int b = 0; b < GX / RSEGS; ++b) sum += p[(size_t)b * HIST_ELEMS];
    unsafeAtomicAdd(&hist[g], sum);
}

static __device__ __forceinline__ float block_reduce_sum(float v, float* buf) {
    for (int off = 32; off > 0; off >>= 1) v += __shfl_down(v, off, 64);
    const int lane = threadIdx.x & 63, wave = threadIdx.x >> 6;
    __syncthreads();
    if (lane == 0) buf[wave] = v;
    __syncthreads();
    return buf[0] + buf[1] + buf[2] + buf[3];
}

__global__ __launch_bounds__(256) void finalize_kernel(const float* __restrict__ ghist,
                                                       float* __restrict__ out) {
    __shared__ float buf[4];
    __shared__ float colp[4][NBINS];
    __shared__ float rowsum[NBINS], colsum[NBINS];
    const int tid = threadIdx.x;
    float acc = 0.0f;
    for (int n = 0; n < 2; ++n) {
        const float* h = ghist + n * HIST_ELEMS;
        {
            int r = tid >> 2, q = tid & 3;
            const float* hp = h + r * NBINS + q * 16;
            float sv = 0.0f;
            #pragma unroll
            for (int k = 0; k < 16; ++k) sv += hp[k];
            sv += __shfl_down(sv, 1, 64);
            sv += __shfl_down(sv, 2, 64);
            if (q == 0) rowsum[r] = sv;
        }
        {
            int c = tid & 63, g = tid >> 6;
            const float* hp = h + (g * 16) * NBINS + c;
            float sv = 0.0f;
            #pragma unroll
            for (int k = 0; k < 16; ++k) sv += hp[k * NBINS];
            colp[g][c] = sv;
        }
        __syncthreads();
        if (tid < NBINS)
            colsum[tid] = colp[0][tid] + colp[1][tid] + colp[2][tid] + colp[3][tid];
        __syncthreads();

        float tv = (tid < NBINS) ? rowsum[tid] : 0.0f;
        float total = block_reduce_sum(tv, buf);
        float inv = 1.0f / total;

        float ej = 0.0f;
        for (int i = tid; i < HIST_ELEMS; i += 256) {
            float p = h[i] * inv;
            ej += p * __logf(p + 1e-10f);
        }
        float entj = -block_reduce_sum(ej, buf);

        float em = 0.0f;
        if (tid < NBINS) {
            float p = rowsum[tid] * inv;
            em = p * __logf(p + 1e-10f);
        } else if (tid < 2 * NBINS) {
            float p = colsum[tid - NBINS] * inv;
            em = p * __logf(p + 1e-10f);
        }
        float ents = -block_reduce_sum(em, buf);

        acc += ents / entj;
        __syncthreads();
    }
    if (tid == 0) out[0] = -0.5f * acc;
}

extern "C" void kernel_launch(void* const* d_in, const int* in_sizes, int n_in,
                              void* d_out, int out_size, void* d_ws, size_t ws_size,
                              hipStream_t stream) {
    const float* tar = (const float*)d_in[0];
    const float* src = (const float*)d_in[1];
    const int N = 2;
    const int P = in_sizes[0] / N;  // 884736

    unsigned* mm = (unsigned*)d_ws;
    float* hist = (float*)((char*)d_ws + 256);
    float* bh = (float*)((char*)d_ws + 256 + 2 * HIST_ELEMS * sizeof(float));
    float* out = (float*)d_out;

    const size_t need = 256 + (size_t)2 * HIST_ELEMS * 4 + (size_t)2 * GX * HIST_ELEMS * 4;

    init_ws_kernel<<<1, 256, 0, stream>>>(mm, hist);
    minmax_kernel<<<dim3(64, N, 2), 256, 0, stream>>>(tar, src, mm, P);
    if (ws_size >= need) {
        mfma_hist_kernel<1><<<dim3(GX, N), 512, 0, stream>>>(tar, src, mm, bh, hist, P);
        reduce_kernel<<<32 * RSEGS, 256, 0, stream>>>(bh, hist);
    } else {
        mfma_hist_kernel<0><<<dim3(GX, N), 512, 0, stream>>>(tar, src, mm, bh, hist, P);
    }
    finalize_kernel<<<1, 256, 0, stream>>>(hist, out);
}

// Round 6
// 224.650 us; speedup vs baseline: 1.3565x; 1.2821x over previous
//
#include <hip/hip_runtime.h>
#include <math.h>

#define NBINS 64
#define HIST_ELEMS (NBINS*NBINS)
#define PTS_PER_BLOCK 2048
#define MEGA 1024
#define MEGAS (PTS_PER_BLOCK/MEGA)
#define GX 432                 // 432 * 2048 = 884736 = P exactly
// weight = exp2(-(u*SQK - b*SQK)^2); SQK = sqrt(8192/63^2*log2(e))
#define SQK 1.7256062f

typedef float f4 __attribute__((ext_vector_type(4)));
typedef float f32x4 __attribute__((ext_vector_type(4)));
typedef _Float16 half8 __attribute__((ext_vector_type(8)));
typedef int int4v __attribute__((ext_vector_type(4)));

// ---- monotone float<->uint keys ----
static __device__ __forceinline__ unsigned f2key(float f) {
    unsigned u = __float_as_uint(f);
    return (u & 0x80000000u) ? ~u : (u | 0x80000000u);
}
static __device__ __forceinline__ float key2f(unsigned u) {
    return (u & 0x80000000u) ? __uint_as_float(u & 0x7fffffffu) : __uint_as_float(~u);
}

static __device__ __forceinline__ half8 pack8(const float* w) {
    int4v v;
    v[0] = __builtin_bit_cast(int, __builtin_amdgcn_cvt_pkrtz(w[0], w[1]));
    v[1] = __builtin_bit_cast(int, __builtin_amdgcn_cvt_pkrtz(w[2], w[3]));
    v[2] = __builtin_bit_cast(int, __builtin_amdgcn_cvt_pkrtz(w[4], w[5]));
    v[3] = __builtin_bit_cast(int, __builtin_amdgcn_cvt_pkrtz(w[6], w[7]));
    return __builtin_bit_cast(half8, v);
}

// ws layout: [0..7] uint minmax keys | @256: float hist[2][4096] | then float bh[2*GX][4096]
__global__ void init_ws_kernel(unsigned* __restrict__ mm, float* __restrict__ hist) {
    int i = threadIdx.x;
    if (i < 8) mm[i] = (i & 1) ? 0u : 0xFFFFFFFFu;
    f4* h4 = (f4*)hist;
    f4 z = {0.f, 0.f, 0.f, 0.f};
    for (int j = i; j < 2 * HIST_ELEMS / 4; j += blockDim.x) h4[j] = z;
}

__global__ __launch_bounds__(256) void minmax_kernel(const float* __restrict__ tar,
                                                     const float* __restrict__ src,
                                                     unsigned* __restrict__ mm, int P) {
    const int n = blockIdx.y;
    const int t = blockIdx.z;
    const f4* x = (const f4*)((t == 0 ? tar : src) + (size_t)n * P);
    const int n4 = P / 4;
    float lmin = INFINITY, lmax = -INFINITY;
    for (int i = blockIdx.x * blockDim.x + threadIdx.x; i < n4; i += gridDim.x * blockDim.x) {
        f4 v = x[i];
        lmin = fminf(lmin, fminf(fminf(v[0], v[1]), fminf(v[2], v[3])));
        lmax = fmaxf(lmax, fmaxf(fmaxf(v[0], v[1]), fmaxf(v[2], v[3])));
    }
    for (int off = 32; off > 0; off >>= 1) {
        lmin = fminf(lmin, __shfl_down(lmin, off, 64));
        lmax = fmaxf(lmax, __shfl_down(lmax, off, 64));
    }
    __shared__ float smin[4], smax[4];
    const int lane = threadIdx.x & 63, wave = threadIdx.x >> 6;
    if (lane == 0) { smin[wave] = lmin; smax[wave] = lmax; }
    __syncthreads();
    if (threadIdx.x == 0) {
        float m = fminf(fminf(smin[0], smin[1]), fminf(smin[2], smin[3]));
        float M = fmaxf(fmaxf(smax[0], smax[1]), fmaxf(smax[2], smax[3]));
        atomicMin(&mm[(n * 2 + t) * 2 + 0], f2key(m));
        atomicMax(&mm[(n * 2 + t) * 2 + 1], f2key(M));
    }
}

// Joint histogram as 64x64xP GEMM via MFMA f16.  R3 structure exactly
// (256 threads, per-mega LDS staging, full unroll); only the grid changed:
// 2048 pts/block x 864 blocks (was 4096 x 432) to double resident waves.
// A[m][k]: m=lane&15 (+16*mt), k=quad*8+j ; B[k][n]: n=lane&15, k=quad*8+j
// C/D: col=lane&15, row=quad*4+reg.
template <int STAGED>
__global__ __launch_bounds__(256) void mfma_hist_kernel(const float* __restrict__ tar,
                                                        const float* __restrict__ src,
                                                        const unsigned* __restrict__ mm,
                                                        float* __restrict__ bh,
                                                        float* __restrict__ hist,
                                                        int P) {
    const int n = blockIdx.y;
    const int bx = blockIdx.x;
    const int tid = threadIdx.x;
    const int lane = tid & 63, wave = tid >> 6;
    const int mlane = lane & 15, quad = lane >> 4;

    __shared__ float su_t[MEGA], su_s[MEGA];
    __shared__ float lh[HIST_ELEMS];
    {
        f4 z = {0.f, 0.f, 0.f, 0.f};
        f4* l4 = (f4*)lh;
        for (int i = tid; i < HIST_ELEMS / 4; i += 256) l4[i] = z;
    }

    const float tmin = key2f(mm[n * 4 + 0]);
    const float tmax = key2f(mm[n * 4 + 1]);
    const float smin = key2f(mm[n * 4 + 2]);
    const float smax = key2f(mm[n * 4 + 3]);
    const float tk = 63.0f / (tmax - tmin + 1e-10f) * SQK;
    const float sk = 63.0f / (smax - smin + 1e-10f) * SQK;

    const float* t = tar + (size_t)n * P + (size_t)bx * PTS_PER_BLOCK;
    const float* s = src + (size_t)n * P + (size_t)bx * PTS_PER_BLOCK;

    float mhat[4];
    #pragma unroll
    for (int mt = 0; mt < 4; ++mt) mhat[mt] = (float)(mlane + 16 * mt) * SQK;

    f32x4 acc[4][4];
    #pragma unroll
    for (int a = 0; a < 4; ++a)
        #pragma unroll
        for (int b = 0; b < 4; ++b) acc[a][b] = (f32x4){0.f, 0.f, 0.f, 0.f};

    for (int mega = 0; mega < MEGAS; ++mega) {
        // --- load phase: 256 threads x 1 float4 each per tensor ---
        const int pb = mega * MEGA + tid * 4;
        f4 tv = *(const f4*)(t + pb);
        f4 sv = *(const f4*)(s + pb);
        f4 utv, usv;
        #pragma unroll
        for (int c = 0; c < 4; ++c) {
            utv[c] = (tv[c] - tmin) * tk;
            usv[c] = (sv[c] - smin) * sk;
        }
        __syncthreads();                 // previous compute done reading LDS
        *(f4*)&su_t[tid * 4] = utv;
        *(f4*)&su_s[tid * 4] = usv;
        __syncthreads();

        // --- compute phase: wave owns 256 points = 8 chunks of K=32 ---
        #pragma unroll
        for (int c = 0; c < 8; ++c) {
            const int kbase = wave * 256 + c * 32 + quad * 8;
            const f4* pt4 = (const f4*)&su_t[kbase];
            const f4* ps4 = (const f4*)&su_s[kbase];
            f4 ta = pt4[0], tb = pt4[1];
            f4 sa = ps4[0], sb = ps4[1];
            float ut[8] = {ta[0], ta[1], ta[2], ta[3], tb[0], tb[1], tb[2], tb[3]};
            float us[8] = {sa[0], sa[1], sa[2], sa[3], sb[0], sb[1], sb[2], sb[3]};

            half8 af[4], bf[4];
            #pragma unroll
            for (int mt = 0; mt < 4; ++mt) {
                float w[8];
                #pragma unroll
                for (int j = 0; j < 8; ++j) {
                    float d = ut[j] - mhat[mt];
                    w[j] = __builtin_amdgcn_exp2f(-(d * d));
                }
                af[mt] = pack8(w);
            }
            #pragma unroll
            for (int nt = 0; nt < 4; ++nt) {
                float w[8];
                #pragma unroll
                for (int j = 0; j < 8; ++j) {
                    float d = us[j] - mhat[nt];
                    w[j] = __builtin_amdgcn_exp2f(-(d * d));
                }
                bf[nt] = pack8(w);
            }
            #pragma unroll
            for (int mt = 0; mt < 4; ++mt)
                #pragma unroll
                for (int nt = 0; nt < 4; ++nt)
                    acc[mt][nt] = __builtin_amdgcn_mfma_f32_16x16x32_f16(
                        af[mt], bf[nt], acc[mt][nt], 0, 0, 0);
        }
    }
    __syncthreads();

    // --- combine 4 waves' 64x64 accumulators in LDS ---
    #pragma unroll
    for (int mt = 0; mt < 4; ++mt)
        #pragma unroll
        for (int nt = 0; nt < 4; ++nt)
            #pragma unroll
            for (int r = 0; r < 4; ++r) {
                int row = 16 * mt + 4 * quad + r;
                int col = 16 * nt + mlane;
                unsafeAtomicAdd(&lh[row * NBINS + col], acc[mt][nt][r]);
            }
    __syncthreads();

    if (STAGED) {
        f4* dst = (f4*)(bh + ((size_t)n * GX + bx) * HIST_ELEMS);
        const f4* l4 = (const f4*)lh;
        for (int i = tid; i < HIST_ELEMS / 4; i += 256) dst[i] = l4[i];
    } else {
        float* gh = hist + (size_t)n * HIST_ELEMS;
        for (int i = tid; i < HIST_ELEMS; i += 256) unsafeAtomicAdd(&gh[i], lh[i]);
    }
}

__global__ __launch_bounds__(256) void reduce_kernel(const float* __restrict__ bh,
                                                     float* __restrict__ hist) {
    const int g = blockIdx.x * 256 + threadIdx.x;   // 0..8191
    const int n = g >> 12, e = g & 4095;
    const float* p = bh + ((size_t)n * GX) * HIST_ELEMS + e;
    float sum = 0.0f;
    #pragma unroll 8
    for (int b = 0; b < GX; ++b) sum += p[(size_t)b * HIST_ELEMS];
    hist[g] = sum;
}

static __device__ __forceinline__ float block_reduce_sum(float v, float* buf) {
    for (int off = 32; off > 0; off >>= 1) v += __shfl_down(v, off, 64);
    const int lane = threadIdx.x & 63, wave = threadIdx.x >> 6;
    __syncthreads();
    if (lane == 0) buf[wave] = v;
    __syncthreads();
    return buf[0] + buf[1] + buf[2] + buf[3];
}

__global__ __launch_bounds__(256) void finalize_kernel(const float* __restrict__ ghist,
                                                       float* __restrict__ out) {
    __shared__ float buf[4];
    __shared__ float colp[4][NBINS];
    __shared__ float rowsum[NBINS], colsum[NBINS];
    const int tid = threadIdx.x;
    float acc = 0.0f;
    for (int n = 0; n < 2; ++n) {
        const float* h = ghist + n * HIST_ELEMS;
        {
            int r = tid >> 2, q = tid & 3;
            const float* hp = h + r * NBINS + q * 16;
            float sv = 0.0f;
            #pragma unroll
            for (int k = 0; k < 16; ++k) sv += hp[k];
            sv += __shfl_down(sv, 1, 64);
            sv += __shfl_down(sv, 2, 64);
            if (q == 0) rowsum[r] = sv;
        }
        {
            int c = tid & 63, g = tid >> 6;
            const float* hp = h + (g * 16) * NBINS + c;
            float sv = 0.0f;
            #pragma unroll
            for (int k = 0; k < 16; ++k) sv += hp[k * NBINS];
            colp[g][c] = sv;
        }
        __syncthreads();
        if (tid < NBINS)
            colsum[tid] = colp[0][tid] + colp[1][tid] + colp[2][tid] + colp[3][tid];
        __syncthreads();

        float tv = (tid < NBINS) ? rowsum[tid] : 0.0f;
        float total = block_reduce_sum(tv, buf);
        float inv = 1.0f / total;

        float ej = 0.0f;
        for (int i = tid; i < HIST_ELEMS; i += 256) {
            float p = h[i] * inv;
            ej += p * __logf(p + 1e-10f);
        }
        float entj = -block_reduce_sum(ej, buf);

        float em = 0.0f;
        if (tid < NBINS) {
            float p = rowsum[tid] * inv;
            em = p * __logf(p + 1e-10f);
        } else if (tid < 2 * NBINS) {
            float p = colsum[tid - NBINS] * inv;
            em = p * __logf(p + 1e-10f);
        }
        float ents = -block_reduce_sum(em, buf);

        acc += ents / entj;
        __syncthreads();
    }
    if (tid == 0) out[0] = -0.5f * acc;
}

extern "C" void kernel_launch(void* const* d_in, const int* in_sizes, int n_in,
                              void* d_out, int out_size, void* d_ws, size_t ws_size,
                              hipStream_t stream) {
    const float* tar = (const float*)d_in[0];
    const float* src = (const float*)d_in[1];
    const int N = 2;
    const int P = in_sizes[0] / N;  // 884736

    unsigned* mm = (unsigned*)d_ws;
    float* hist = (float*)((char*)d_ws + 256);
    float* bh = (float*)((char*)d_ws + 256 + 2 * HIST_ELEMS * sizeof(float));
    float* out = (float*)d_out;

    const size_t need = 256 + (size_t)2 * HIST_ELEMS * 4 + (size_t)2 * GX * HIST_ELEMS * 4;

    init_ws_kernel<<<1, 256, 0, stream>>>(mm, hist);
    minmax_kernel<<<dim3(64, N, 2), 256, 0, stream>>>(tar, src, mm, P);
    if (ws_size >= need) {
        mfma_hist_kernel<1><<<dim3(GX, N), 256, 0, stream>>>(tar, src, mm, bh, hist, P);
        reduce_kernel<<<32, 256, 0, stream>>>(bh, hist);
    } else {
        mfma_hist_kernel<0><<<dim3(GX, N), 256, 0, stream>>>(tar, src, mm, bh, hist, P);
    }
    finalize_kernel<<<1, 256, 0, stream>>>(hist, out);
}

// Round 7
// 174.907 us; speedup vs baseline: 1.7423x; 1.2844x over previous
//
#include <hip/hip_runtime.h>
#include <math.h>

#define NBINS 64
#define HIST_ELEMS (NBINS*NBINS)
#define PTS_PER_BLOCK 3456      // 256 blocks/n * 3456 = 884736 = P exactly; 512 blocks = 2/CU even
#define GXN 256                 // blocks per sample
// weight = exp2(-(u*SQK - b*SQK)^2); SQK = sqrt(8192/63^2*log2(e))
#define SQK 1.7256062f

typedef float f4 __attribute__((ext_vector_type(4)));
typedef float f32x4 __attribute__((ext_vector_type(4)));
typedef _Float16 half8 __attribute__((ext_vector_type(8)));
typedef int int4v __attribute__((ext_vector_type(4)));

// ---- monotone float<->uint keys ----
static __device__ __forceinline__ unsigned f2key(float f) {
    unsigned u = __float_as_uint(f);
    return (u & 0x80000000u) ? ~u : (u | 0x80000000u);
}
static __device__ __forceinline__ float key2f(unsigned u) {
    return (u & 0x80000000u) ? __uint_as_float(u & 0x7fffffffu) : __uint_as_float(~u);
}

static __device__ __forceinline__ half8 pack8(const float* w) {
    int4v v;
    v[0] = __builtin_bit_cast(int, __builtin_amdgcn_cvt_pkrtz(w[0], w[1]));
    v[1] = __builtin_bit_cast(int, __builtin_amdgcn_cvt_pkrtz(w[2], w[3]));
    v[2] = __builtin_bit_cast(int, __builtin_amdgcn_cvt_pkrtz(w[4], w[5]));
    v[3] = __builtin_bit_cast(int, __builtin_amdgcn_cvt_pkrtz(w[6], w[7]));
    return __builtin_bit_cast(half8, v);
}

// ws layout: uint mm[8]: [0..3]=min keys (idx n*2+t, memset 0xFF), [4..7]=max keys (memset 0x00)
//            @256: float hist[2][4096] | @33024: float bh[2*GXN][4096]
__global__ __launch_bounds__(256) void minmax_kernel(const float* __restrict__ tar,
                                                     const float* __restrict__ src,
                                                     unsigned* __restrict__ mm, int P) {
    const int n = blockIdx.y;
    const int t = blockIdx.z;
    const f4* x = (const f4*)((t == 0 ? tar : src) + (size_t)n * P);
    const int n4 = P / 4;
    float lmin = INFINITY, lmax = -INFINITY;
    for (int i = blockIdx.x * blockDim.x + threadIdx.x; i < n4; i += gridDim.x * blockDim.x) {
        f4 v = x[i];
        lmin = fminf(lmin, fminf(fminf(v[0], v[1]), fminf(v[2], v[3])));
        lmax = fmaxf(lmax, fmaxf(fmaxf(v[0], v[1]), fmaxf(v[2], v[3])));
    }
    for (int off = 32; off > 0; off >>= 1) {
        lmin = fminf(lmin, __shfl_down(lmin, off, 64));
        lmax = fmaxf(lmax, __shfl_down(lmax, off, 64));
    }
    __shared__ float smin[4], smax[4];
    const int lane = threadIdx.x & 63, wave = threadIdx.x >> 6;
    if (lane == 0) { smin[wave] = lmin; smax[wave] = lmax; }
    __syncthreads();
    if (threadIdx.x == 0) {
        float m = fminf(fminf(smin[0], smin[1]), fminf(smin[2], smin[3]));
        float M = fmaxf(fmaxf(smax[0], smax[1]), fmaxf(smax[2], smax[3]));
        atomicMin(&mm[n * 2 + t], f2key(m));
        atomicMax(&mm[4 + n * 2 + t], f2key(M));
    }
}

// Joint histogram as 64x64xP GEMM via MFMA f16.  R3 compute core; one staging
// phase per block (3456 pts, 27.6 KB LDS), 27 K=32 chunks per wave, 2 barriers
// per block total.  Grid 512 blocks = exactly 2 per CU (even rounds).
// A[m][k]: m=lane&15 (+16*mt), k=quad*8+j ; B[k][n]: n=lane&15, k=quad*8+j
// C/D: col=lane&15, row=quad*4+reg.
template <int STAGED>
__global__ __launch_bounds__(256) void mfma_hist_kernel(const float* __restrict__ tar,
                                                        const float* __restrict__ src,
                                                        const unsigned* __restrict__ mm,
                                                        float* __restrict__ bh,
                                                        float* __restrict__ hist,
                                                        int P) {
    const int n = blockIdx.y;
    const int bx = blockIdx.x;
    const int tid = threadIdx.x;
    const int lane = tid & 63, wave = tid >> 6;
    const int mlane = lane & 15, quad = lane >> 4;

    __shared__ float su_t[PTS_PER_BLOCK], su_s[PTS_PER_BLOCK];
    __shared__ float lh[HIST_ELEMS];
    {
        f4 z = {0.f, 0.f, 0.f, 0.f};
        f4* l4 = (f4*)lh;
        for (int i = tid; i < HIST_ELEMS / 4; i += 256) l4[i] = z;
    }

    const float tmin = key2f(mm[n * 2 + 0]);
    const float tmax = key2f(mm[4 + n * 2 + 0]);
    const float smin = key2f(mm[n * 2 + 1]);
    const float smax = key2f(mm[4 + n * 2 + 1]);
    const float tk = 63.0f / (tmax - tmin + 1e-10f) * SQK;
    const float sk = 63.0f / (smax - smin + 1e-10f) * SQK;
    const float toff = tmin * tk, soff = smin * sk;

    // --- single staging phase: 864 f4 per tensor, coalesced ---
    {
        const f4* tg = (const f4*)(tar + (size_t)n * P + (size_t)bx * PTS_PER_BLOCK);
        const f4* sg = (const f4*)(src + (size_t)n * P + (size_t)bx * PTS_PER_BLOCK);
        f4* st4 = (f4*)su_t;
        f4* ss4 = (f4*)su_s;
        #pragma unroll
        for (int k = 0; k < 3; ++k) {
            const int i = tid + k * 256;
            f4 tv = tg[i], sv = sg[i];
            f4 utv, usv;
            #pragma unroll
            for (int c = 0; c < 4; ++c) {
                utv[c] = fmaf(tv[c], tk, -toff);
                usv[c] = fmaf(sv[c], sk, -soff);
            }
            st4[i] = utv;
            ss4[i] = usv;
        }
        if (tid < 96) {
            const int i = 768 + tid;
            f4 tv = tg[i], sv = sg[i];
            f4 utv, usv;
            #pragma unroll
            for (int c = 0; c < 4; ++c) {
                utv[c] = fmaf(tv[c], tk, -toff);
                usv[c] = fmaf(sv[c], sk, -soff);
            }
            st4[i] = utv;
            ss4[i] = usv;
        }
    }
    __syncthreads();   // staging + lh zeroing complete

    float mhat[4];
    #pragma unroll
    for (int mt = 0; mt < 4; ++mt) mhat[mt] = (float)(mlane + 16 * mt) * SQK;

    f32x4 acc[4][4];
    #pragma unroll
    for (int a = 0; a < 4; ++a)
        #pragma unroll
        for (int b = 0; b < 4; ++b) acc[a][b] = (f32x4){0.f, 0.f, 0.f, 0.f};

    // --- compute: wave owns 864 points = 27 chunks of K=32, barrier-free ---
    const int kwbase = wave * 864 + quad * 8;
    #pragma unroll 3
    for (int c = 0; c < 27; ++c) {
        const int kbase = kwbase + c * 32;
        const f4* pt4 = (const f4*)&su_t[kbase];
        const f4* ps4 = (const f4*)&su_s[kbase];
        f4 ta = pt4[0], tb = pt4[1];
        f4 sa = ps4[0], sb = ps4[1];
        float ut[8] = {ta[0], ta[1], ta[2], ta[3], tb[0], tb[1], tb[2], tb[3]};
        float us[8] = {sa[0], sa[1], sa[2], sa[3], sb[0], sb[1], sb[2], sb[3]};

        half8 af[4], bf[4];
        #pragma unroll
        for (int mt = 0; mt < 4; ++mt) {
            float w[8];
            #pragma unroll
            for (int j = 0; j < 8; ++j) {
                float d = ut[j] - mhat[mt];
                w[j] = __builtin_amdgcn_exp2f(-(d * d));
            }
            af[mt] = pack8(w);
        }
        #pragma unroll
        for (int nt = 0; nt < 4; ++nt) {
            float w[8];
            #pragma unroll
            for (int j = 0; j < 8; ++j) {
                float d = us[j] - mhat[nt];
                w[j] = __builtin_amdgcn_exp2f(-(d * d));
            }
            bf[nt] = pack8(w);
        }
        #pragma unroll
        for (int mt = 0; mt < 4; ++mt)
            #pragma unroll
            for (int nt = 0; nt < 4; ++nt)
                acc[mt][nt] = __builtin_amdgcn_mfma_f32_16x16x32_f16(
                    af[mt], bf[nt], acc[mt][nt], 0, 0, 0);
    }

    // --- combine 4 waves' 64x64 accumulators in LDS ---
    // (ordering vs lh zeroing guaranteed by the staging barrier; atomics race-safe)
    #pragma unroll
    for (int mt = 0; mt < 4; ++mt)
        #pragma unroll
        for (int nt = 0; nt < 4; ++nt)
            #pragma unroll
            for (int r = 0; r < 4; ++r) {
                int row = 16 * mt + 4 * quad + r;
                int col = 16 * nt + mlane;
                unsafeAtomicAdd(&lh[row * NBINS + col], acc[mt][nt][r]);
            }
    __syncthreads();

    if (STAGED) {
        f4* dst = (f4*)(bh + ((size_t)n * GXN + bx) * HIST_ELEMS);
        const f4* l4 = (const f4*)lh;
        for (int i = tid; i < HIST_ELEMS / 4; i += 256) dst[i] = l4[i];
    } else {
        float* gh = hist + (size_t)n * HIST_ELEMS;
        for (int i = tid; i < HIST_ELEMS; i += 256) unsafeAtomicAdd(&gh[i], lh[i]);
    }
}

__global__ __launch_bounds__(256) void reduce_kernel(const float* __restrict__ bh,
                                                     float* __restrict__ hist) {
    const int g = blockIdx.x * 256 + threadIdx.x;   // 0..8191
    const int n = g >> 12, e = g & 4095;
    const float* p = bh + ((size_t)n * GXN) * HIST_ELEMS + e;
    float sum = 0.0f;
    #pragma unroll 8
    for (int b = 0; b < GXN; ++b) sum += p[(size_t)b * HIST_ELEMS];
    hist[g] = sum;
}

static __device__ __forceinline__ float block_reduce_sum(float v, float* buf) {
    for (int off = 32; off > 0; off >>= 1) v += __shfl_down(v, off, 64);
    const int lane = threadIdx.x & 63, wave = threadIdx.x >> 6;
    __syncthreads();
    if (lane == 0) buf[wave] = v;
    __syncthreads();
    return buf[0] + buf[1] + buf[2] + buf[3];
}

__global__ __launch_bounds__(256) void finalize_kernel(const float* __restrict__ ghist,
                                                       float* __restrict__ out) {
    __shared__ float buf[4];
    __shared__ float colp[4][NBINS];
    __shared__ float rowsum[NBINS], colsum[NBINS];
    const int tid = threadIdx.x;
    float acc = 0.0f;
    for (int n = 0; n < 2; ++n) {
        const float* h = ghist + n * HIST_ELEMS;
        {
            int r = tid >> 2, q = tid & 3;
            const float* hp = h + r * NBINS + q * 16;
            float sv = 0.0f;
            #pragma unroll
            for (int k = 0; k < 16; ++k) sv += hp[k];
            sv += __shfl_down(sv, 1, 64);
            sv += __shfl_down(sv, 2, 64);
            if (q == 0) rowsum[r] = sv;
        }
        {
            int c = tid & 63, g = tid >> 6;
            const float* hp = h + (g * 16) * NBINS + c;
            float sv = 0.0f;
            #pragma unroll
            for (int k = 0; k < 16; ++k) sv += hp[k * NBINS];
            colp[g][c] = sv;
        }
        __syncthreads();
        if (tid < NBINS)
            colsum[tid] = colp[0][tid] + colp[1][tid] + colp[2][tid] + colp[3][tid];
        __syncthreads();

        float tv = (tid < NBINS) ? rowsum[tid] : 0.0f;
        float total = block_reduce_sum(tv, buf);
        float inv = 1.0f / total;

        float ej = 0.0f;
        for (int i = tid; i < HIST_ELEMS; i += 256) {
            float p = h[i] * inv;
            ej += p * __logf(p + 1e-10f);
        }
        float entj = -block_reduce_sum(ej, buf);

        float em = 0.0f;
        if (tid < NBINS) {
            float p = rowsum[tid] * inv;
            em = p * __logf(p + 1e-10f);
        } else if (tid < 2 * NBINS) {
            float p = colsum[tid - NBINS] * inv;
            em = p * __logf(p + 1e-10f);
        }
        float ents = -block_reduce_sum(em, buf);

        acc += ents / entj;
        __syncthreads();
    }
    if (tid == 0) out[0] = -0.5f * acc;
}

extern "C" void kernel_launch(void* const* d_in, const int* in_sizes, int n_in,
                              void* d_out, int out_size, void* d_ws, size_t ws_size,
                              hipStream_t stream) {
    const float* tar = (const float*)d_in[0];
    const float* src = (const float*)d_in[1];
    const int N = 2;
    const int P = in_sizes[0] / N;  // 884736

    unsigned* mm = (unsigned*)d_ws;
    float* hist = (float*)((char*)d_ws + 256);
    float* bh = (float*)((char*)d_ws + 256 + 2 * HIST_ELEMS * sizeof(float));
    float* out = (float*)d_out;

    const size_t need = 256 + (size_t)2 * HIST_ELEMS * 4 + (size_t)2 * GXN * HIST_ELEMS * 4;

    // mm init via async memsets: min-key slots -> 0xFFFFFFFF, max-key slots -> 0
    hipMemsetAsync(d_ws, 0xFF, 16, stream);
    hipMemsetAsync((char*)d_ws + 16, 0x00, 16, stream);
    minmax_kernel<<<dim3(64, N, 2), 256, 0, stream>>>(tar, src, mm, P);
    if (ws_size >= need) {
        mfma_hist_kernel<1><<<dim3(GXN, N), 256, 0, stream>>>(tar, src, mm, bh, hist, P);
        reduce_kernel<<<32, 256, 0, stream>>>(bh, hist);
    } else {
        hipMemsetAsync((char*)d_ws + 256, 0x00, 2 * HIST_ELEMS * sizeof(float), stream);
        mfma_hist_kernel<0><<<dim3(GXN, N), 256, 0, stream>>>(tar, src, mm, bh, hist, P);
    }
    finalize_kernel<<<1, 256, 0, stream>>>(hist, out);
}